// Round 36
// baseline (70.510 us; speedup 1.0000x reference)
//
#include <hip/hip_runtime.h>
#include <utility>

#define D_DIM 256
#define WID   33
#define CEN   16
#define RITER 16                 // output rows per iteration
#define NI    8                  // iterations per block
#define CHUNK (RITER * NI)       // 128 output rows per block
#define RING  64                 // ring slots (x rows)
#define PROL  48                 // prologue staged rows
#define BCH   1024               // dwords per B chunk (256 cols x 4 dwords)
#define ASTRD 40                 // dwords per A row (80 u16 = 64 k + pad)

// R35 post-mortem: MFMA concept worked (VALUBusy 26->9%) but two impl bugs:
// (1) Bl [col][slot] stride-36dw -> 8-way bank conflicts on staging writes
//     (1.4M). Fix: B as [slot/8][col][8-slot 16B] -> frag reads AND uint4
//     writes are 16B-consecutive per lane, conflict-free.
// (2) scalar dword NT stores -> sub-128B HBM writes, WRITE 131->175MB.
//     Fix: plain stores (L2 write-combines). A-stride 40dw (4-way max).
// Bonus: LDS ~37.5KB -> 4 blocks/CU (2x R34's occupancy).
// Fragment layouts unchanged from R35 (verified: absmax 0.0625).

typedef float  f32x4  __attribute__((ext_vector_type(4)));
typedef __bf16 bf16x8 __attribute__((ext_vector_type(8)));

__device__ __forceinline__ int clampN(int p, int N) {
    return p < 0 ? 0 : (p >= N ? N - 1 : p);
}

__device__ __forceinline__ unsigned short bfb(float f) {
    __bf16 b = (__bf16)f;
    return __builtin_bit_cast(unsigned short, b);
}

__device__ __forceinline__ unsigned packbf(float lo, float hi) {
    return (unsigned)bfb(lo) | ((unsigned)bfb(hi) << 16);
}

__device__ __forceinline__ bf16x8 ldfragd(const unsigned* dw) {
    const uint4 v = *reinterpret_cast<const uint4*>(dw);
    return __builtin_bit_cast(bf16x8, v);
}

// ---- B staging: this thread's column, 16 rows ----
template <size_t... Js>
__device__ __forceinline__ void loadB(float (&xv)[RITER],
                                      const float* __restrict__ xgl,
                                      int rowb, int N,
                                      std::index_sequence<Js...>) {
    ((xv[Js] = xgl[(size_t)clampN(rowb + (int)Js, N) * D_DIM]), ...);
}

__device__ __forceinline__ void writeB(unsigned* Bl, const float (&xv)[RITER],
                                       int col, int sb) {          // sb % 16 == 0
    uint4 w0, w1;
    w0.x = packbf(xv[0],  xv[1]);  w0.y = packbf(xv[2],  xv[3]);
    w0.z = packbf(xv[4],  xv[5]);  w0.w = packbf(xv[6],  xv[7]);
    w1.x = packbf(xv[8],  xv[9]);  w1.y = packbf(xv[10], xv[11]);
    w1.z = packbf(xv[12], xv[13]); w1.w = packbf(xv[14], xv[15]);
    *(uint4*)(Bl + (sb >> 3) * BCH + col * 4) = w0;                // conflict-free
    *(uint4*)(Bl + ((sb >> 3) + 1) * BCH + col * 4) = w1;          // (16B/lane)
}

template <size_t... Ps>
__device__ __forceinline__ void prologueB(unsigned* Bl,
                                          const float* __restrict__ xgl,
                                          int base, int N, int col,
                                          std::index_sequence<Ps...>) {
    (([&] {
         const float f0 = xgl[(size_t)clampN(base + 2 * (int)Ps, N) * D_DIM];
         const float f1 = xgl[(size_t)clampN(base + 2 * (int)Ps + 1, N) * D_DIM];
         Bl[((int)Ps >> 2) * BCH + col * 4 + ((int)Ps & 3)] = packbf(f0, f1);
     }()),
     ...);
}

// ---- A staging: banded weights, zero-filled (taps AND x-row bounds) ----
template <size_t... Js>
__device__ __forceinline__ void loadA(float (&wf)[4],
                                      const float* __restrict__ smb,
                                      int R, int g, int k0, int N,
                                      std::index_sequence<Js...>) {
    const int cap = N * WID - 1;
    (([&] {
         int idx = (R + g) * WID + k0 + (int)Js - g;
         idx = idx < 0 ? 0 : (idx > cap ? cap : idx);
         wf[Js] = smb[(size_t)idx];
     }()),
     ...);
}

__device__ __forceinline__ void writeA(unsigned* AlB, const float (&wf)[4],
                                       int R, int g, int k0, int N) {
    float v[4];
#pragma unroll
    for (int j = 0; j < 4; ++j) {
        const int k = k0 + j;
        const unsigned tap = (unsigned)(k - g);
        const int xr = R - CEN + k;
        v[j] = (tap < (unsigned)WID && (unsigned)xr < (unsigned)N) ? wf[j] : 0.0f;
    }
    uint2 aw;
    aw.x = packbf(v[0], v[1]);
    aw.y = packbf(v[2], v[3]);
    *(uint2*)(AlB + g * ASTRD + (k0 >> 1)) = aw;
}

template <size_t... Js>
__device__ __forceinline__ void loadSZ(float (&sz)[4],
                                       const float* __restrict__ szb,
                                       int R, int q4, int N,
                                       std::index_sequence<Js...>) {
    ((sz[Js] = szb[clampN(R + q4 + (int)Js, N)]), ...);
}

// ---- compute: 8 MFMA per wave (4 col-tiles x 2 K-steps) ----
template <size_t... Is>
__device__ __forceinline__ void compute(f32x4 (&acc)[4], const unsigned* Bl,
                                        const unsigned* AlB, int s0, int wv,
                                        int lane, std::index_sequence<Is...>) {
    const int g  = lane & 15;
    const int q8 = (lane >> 4) * 8;
    const bf16x8 af0 = ldfragd(AlB + g * ASTRD + (q8 >> 1));
    const bf16x8 af1 = ldfragd(AlB + g * ASTRD + (q8 >> 1) + 16);
    const int sA = (s0 + q8) & (RING - 1);
    const int sB = (s0 + q8 + 32) & (RING - 1);
    (([&] {
         const int col = (wv * 4 + (int)Is) * 16 + g;
         const bf16x8 b0 = ldfragd(Bl + (sA >> 3) * BCH + col * 4);
         const bf16x8 b1 = ldfragd(Bl + (sB >> 3) * BCH + col * 4);
         acc[Is] = __builtin_amdgcn_mfma_f32_16x16x32_bf16(af0, b0, acc[Is], 0, 0, 0);
         acc[Is] = __builtin_amdgcn_mfma_f32_16x16x32_bf16(af1, b1, acc[Is], 0, 0, 0);
     }()),
     ...);
}

// ---- epilogue: scale + plain stores (C: col=lane&15, row=(l>>4)*4+reg) ----
template <size_t... Ts>
__device__ __forceinline__ void epi(const f32x4 (&acc)[4], const float (&sz)[4],
                                    float* __restrict__ obase, int R0m,
                                    std::index_sequence<Ts...>) {
    float inv[4];
#pragma unroll
    for (int j = 0; j < 4; ++j)
        inv[j] = __builtin_amdgcn_rcpf(fmaxf(sz[j], 1e-6f));
    (([&] {
         constexpr int i = (int)Ts / 4, j = (int)Ts % 4;
         obase[(size_t)(R0m + j) * D_DIM + i * 16] = acc[i][j] * inv[j];
     }()),
     ...);
}

__global__ __launch_bounds__(256) void local_enc_kernel(
    const float* __restrict__ x, const float* __restrict__ sizev,
    const float* __restrict__ sm, float* __restrict__ out, int N) {
    __shared__ unsigned Bl[8 * BCH];         // 32 KB: [chunk][col][8-slot]
    __shared__ unsigned Al[2][16 * ASTRD];   // 2 x 2.5 KB: banded weights

    // XCD swizzle: XCD k owns batch k, strips consecutive -> L2-local
    const int bid   = blockIdx.x;
    const int swz   = (bid & 7) * 128 + (bid >> 3);
    const int strip = swz & 127;
    const int b     = swz >> 7;
    const int n0    = strip * CHUNK;
    const int tid   = threadIdx.x;
    const int wv    = tid >> 6;
    const int lane  = tid & 63;

    const size_t bN = (size_t)b * (size_t)N;
    const float* __restrict__ xgl = x + bN * D_DIM + tid;    // col = tid
    const float* __restrict__ smb = sm + bN * WID;
    const float* __restrict__ szb = sizev + bN;

    const int g  = tid & 15;          // A staging: output row
    const int k0 = (tid >> 4) * 4;    // A staging: k base (0..60)
    const int q4 = (lane >> 4) * 4;   // epilogue row quarter

    float* __restrict__ obase =
        out + (bN + (size_t)q4) * D_DIM + wv * 64 + (lane & 15);

    // ---- prologue ----
    prologueB(Bl, xgl, n0 - CEN, N, tid, std::make_index_sequence<PROL / 2>{});
#pragma unroll
    for (int p = 0; p < 8; ++p)              // zero slots 48..63 (chunks 6,7)
        Bl[(6 + (p >> 2)) * BCH + tid * 4 + (p & 3)] = 0;

    float wf0[4];
    loadA(wf0, smb, n0, g, k0, N, std::make_index_sequence<4>{});
    writeA(Al[0], wf0, n0, g, k0, N);

    float szc[4];
    loadSZ(szc, szb, n0, q4, N, std::make_index_sequence<4>{});
    __syncthreads();

    // ---- main loop ----
#pragma unroll 1
    for (int m = 0; m < NI; ++m) {
        const int R0m = n0 + RITER * m;
        const bool more = (m < NI - 1);

        // phase 1: issue next-tile loads (land under compute)
        float xv[RITER];
        float wfn[4];
        float szn[4];
        if (more) {
            loadB(xv, xgl, R0m + 32, N, std::make_index_sequence<RITER>{});
            loadA(wfn, smb, R0m + RITER, g, k0, N, std::make_index_sequence<4>{});
            loadSZ(szn, szb, R0m + RITER, q4, N, std::make_index_sequence<4>{});
        }
        __builtin_amdgcn_sched_barrier(0);

        // phase 2: MFMA compute from the ring
        const int s0 = (RITER * m) & (RING - 1);
        f32x4 acc[4] = {};
        compute(acc, Bl, Al[m & 1], s0, wv, lane, std::make_index_sequence<4>{});
        epi(acc, szc, obase, R0m, std::make_index_sequence<16>{});

        // phase 3: cvt + LDS writes (read slots only overlap where A=0)
        if (more) {
            writeB(Bl, xv, tid, (PROL + RITER * m) & (RING - 1));
            writeA(Al[(m + 1) & 1], wfn, R0m + RITER, g, k0, N);
#pragma unroll
            for (int j = 0; j < 4; ++j) szc[j] = szn[j];
        }
        __syncthreads();
    }
}

extern "C" void kernel_launch(void* const* d_in, const int* in_sizes, int n_in,
                              void* d_out, int out_size, void* d_ws, size_t ws_size,
                              hipStream_t stream) {
    const float* x  = (const float*)d_in[0];
    const float* sz = (const float*)d_in[1];
    const float* sm = (const float*)d_in[2];
    float* out = (float*)d_out;

    const int B = 8;
    const int N = 16384;

    dim3 grid((N / CHUNK) * B, 1, 1);   // 128 x 8 = 1024 blocks = 4 per CU
    dim3 block(256, 1, 1);
    local_enc_kernel<<<grid, block, 0, stream>>>(x, sz, sm, out, N);
}

// Round 37
// 60.190 us; speedup vs baseline: 1.1714x; 1.1714x over previous
//
#include <hip/hip_runtime.h>
#include <utility>

#define D_DIM 256
#define WID   33
#define CEN   16
#define RITER 16                 // output rows per iteration
#define NI    16                 // iterations per block
#define CHUNK (RITER * NI)       // 256 output rows per block
#define RING  64                 // ring slots (fp32 rows, identity mapping)
#define PROL  48                 // prologue staged rows
#define SLOTD 256                // dwords per slot (1 KB)
#define ASTRD 40                 // dwords per A row (80 u16 = 64 k + pad)

// R36 post-mortem: MFMA shrank compute to ~300cy -> reg-staged loads had
// nothing to hide under (T14 prereq destroyed). Fix: R34's PROVEN async-DMA
// fp32 ring (VGPR-free, spans counted barriers) + MFMA core. The ring uses
// IDENTITY slot mapping (slot = (row+16)&63, no per-read rotation); the
// k-rotation moves into the A-tile staging (A[g][kappa] pre-rotated with
// kw=(kappa-16m)&63, zero-filled for invalid taps/OOB rows). B-frags then
// read via 64 ds_read_b32 at compile-time offsets off one per-lane base +
// v_cvt_pk to bf16 (~6x less LDS+VALU than R34's scalar core). Counted
// barrier vmcnt(21)+lgkmcnt(0). Slots 48..63: A=0 (prologue zeroes once).

typedef float  f32x4  __attribute__((ext_vector_type(4)));
typedef __bf16 bf16x8 __attribute__((ext_vector_type(8)));

__device__ __forceinline__ int clampN(int p, int N) {
    return p < 0 ? 0 : (p >= N ? N - 1 : p);
}

__device__ __forceinline__ unsigned short bfb(float f) {
    __bf16 b = (__bf16)f;
    return __builtin_bit_cast(unsigned short, b);
}

__device__ __forceinline__ unsigned packbf(float lo, float hi) {
    return (unsigned)bfb(lo) | ((unsigned)bfb(hi) << 16);
}

__device__ __forceinline__ bf16x8 ldfragd(const unsigned* dw) {
    const uint4 v = *reinterpret_cast<const uint4*>(dw);
    return __builtin_bit_cast(bf16x8, v);
}

__device__ __forceinline__ void dma_row(float* xs, int slot,
                                        const float* __restrict__ xlane,
                                        int row) {
    __builtin_amdgcn_global_load_lds(
        (const __attribute__((address_space(1))) void*)(xlane +
                                                        (size_t)row * D_DIM),
        (__attribute__((address_space(3))) void*)(xs + slot * SLOTD), 16, 0, 0);
}

template <size_t... Ss>
__device__ __forceinline__ void stage_prol(float* xs,
                                           const float* __restrict__ xlane,
                                           int base0, int N, int wv,
                                           std::index_sequence<Ss...>) {
    (([&] {
         const int s = wv * (PROL / 4) + (int)Ss;      // 12 rows per wave
         dma_row(xs, s, xlane, clampN(base0 + s, N));
     }()),
     ...);
}

// stage 16 rows (4 per wave): row n0+32+16m+k -> slot (48+16m+k) & 63
__device__ __forceinline__ void stage_iter(float* xs,
                                           const float* __restrict__ xlane,
                                           int base0, int m, int N, int wv) {
#pragma unroll
    for (int kk = 0; kk < 4; ++kk) {
        const int k = wv * 4 + kk;
        const int s = (PROL + RITER * m + k) & (RING - 1);
        dma_row(xs, s, xlane, clampN(base0 + PROL + RITER * m + k, N));
    }
}

// ---- A staging: pre-rotated banded weights for target iter mt ----
template <size_t... Js>
__device__ __forceinline__ void loadA(float (&wf)[4],
                                      const float* __restrict__ smb,
                                      int R0, int g, int k0, int mt,
                                      std::index_sequence<Js...>) {
    (([&] {
         const int kw  = (k0 + (int)Js - RITER * mt) & (RING - 1);
         int tap = kw - g;
         tap = tap < 0 ? 0 : (tap > 32 ? 32 : tap);
         wf[Js] = smb[(size_t)(R0 + g) * WID + tap];   // R0+g < N always
     }()),
     ...);
}

__device__ __forceinline__ void writeA(unsigned* AlB, const float (&wf)[4],
                                       int R0, int g, int k0, int mt, int N) {
    float v[4];
#pragma unroll
    for (int j = 0; j < 4; ++j) {
        const int kw  = (k0 + j - RITER * mt) & (RING - 1);
        const int tap = kw - g;
        const int xr  = R0 - CEN + kw;
        v[j] = ((unsigned)tap < (unsigned)WID && (unsigned)xr < (unsigned)N)
                   ? wf[j] : 0.0f;
    }
    uint2 aw;
    aw.x = packbf(v[0], v[1]);
    aw.y = packbf(v[2], v[3]);
    *(uint2*)(AlB + g * ASTRD + (k0 >> 1)) = aw;
}

template <size_t... Js>
__device__ __forceinline__ void loadSZ(float (&sz)[4],
                                       const float* __restrict__ szb,
                                       int R, int q4, int N,
                                       std::index_sequence<Js...>) {
    ((sz[Js] = szb[clampN(R + q4 + (int)Js, N)]), ...);
}

// ---- B fragment: 8 fp32 ring reads (compile-time offsets) + cvt ----
template <int KS, int IS>
__device__ __forceinline__ bf16x8 bfrag(const float* xsb) {
    uint4 r;
    r.x = packbf(xsb[(KS * 32 + 0) * SLOTD + IS * 16],
                 xsb[(KS * 32 + 1) * SLOTD + IS * 16]);
    r.y = packbf(xsb[(KS * 32 + 2) * SLOTD + IS * 16],
                 xsb[(KS * 32 + 3) * SLOTD + IS * 16]);
    r.z = packbf(xsb[(KS * 32 + 4) * SLOTD + IS * 16],
                 xsb[(KS * 32 + 5) * SLOTD + IS * 16]);
    r.w = packbf(xsb[(KS * 32 + 6) * SLOTD + IS * 16],
                 xsb[(KS * 32 + 7) * SLOTD + IS * 16]);
    return __builtin_bit_cast(bf16x8, r);
}

template <size_t... Is>
__device__ __forceinline__ void compute(f32x4 (&acc)[4], const float* xsb,
                                        const unsigned* AlB, int g, int q8,
                                        std::index_sequence<Is...>) {
    const bf16x8 af0 = ldfragd(AlB + g * ASTRD + (q8 >> 1));
    const bf16x8 af1 = ldfragd(AlB + g * ASTRD + (q8 >> 1) + 16);
    (([&] {
         const bf16x8 b0 = bfrag<0, (int)Is>(xsb);
         const bf16x8 b1 = bfrag<1, (int)Is>(xsb);
         acc[Is] = __builtin_amdgcn_mfma_f32_16x16x32_bf16(af0, b0, acc[Is], 0, 0, 0);
         acc[Is] = __builtin_amdgcn_mfma_f32_16x16x32_bf16(af1, b1, acc[Is], 0, 0, 0);
     }()),
     ...);
}

// ---- epilogue: scale + plain stores (C: col=lane&15, row=(l>>4)*4+reg) ----
template <size_t... Ts>
__device__ __forceinline__ void epi(const f32x4 (&acc)[4], const float (&sz)[4],
                                    float* __restrict__ obase, int R0m,
                                    std::index_sequence<Ts...>) {
    float inv[4];
#pragma unroll
    for (int j = 0; j < 4; ++j)
        inv[j] = __builtin_amdgcn_rcpf(fmaxf(sz[j], 1e-6f));
    (([&] {
         constexpr int i = (int)Ts / 4, j = (int)Ts % 4;
         obase[(size_t)(R0m + j) * D_DIM + i * 16] = acc[i][j] * inv[j];
     }()),
     ...);
}

__global__ __launch_bounds__(256) void local_enc_kernel(
    const float* __restrict__ x, const float* __restrict__ sizev,
    const float* __restrict__ sm, float* __restrict__ out, int N) {
    __shared__ float xs[RING * SLOTD];       // 64 KB fp32 ring
    __shared__ unsigned Al[2][16 * ASTRD];   // 2 x 2.5 KB pre-rotated A

    // XCD swizzle: XCD k owns batch k, strips consecutive -> L2-local
    const int bid   = blockIdx.x;
    const int swz   = (bid & 7) * 64 + (bid >> 3);
    const int strip = swz & 63;
    const int b     = swz >> 6;
    const int n0    = strip * CHUNK;
    const int tid   = threadIdx.x;
    const int wv    = tid >> 6;
    const int lane  = tid & 63;

    const size_t bN = (size_t)b * (size_t)N;
    const float* __restrict__ xlane = x + bN * D_DIM + lane * 4;
    const float* __restrict__ smb   = sm + bN * WID;
    const float* __restrict__ szb   = sizev + bN;

    const int g  = tid & 15;          // A staging: output row
    const int k0 = (tid >> 4) * 4;    // A staging: kappa base (0..60)
    const int q8 = (lane >> 4) * 8;   // fragment k-group
    const int q4 = (lane >> 4) * 4;   // epilogue row quarter

    const float* xsb = xs + q8 * SLOTD + wv * 64 + (lane & 15);
    float* __restrict__ obase =
        out + (bN + (size_t)q4) * D_DIM + wv * 64 + (lane & 15);

    // ---- prologue ----
    stage_prol(xs, xlane, n0 - CEN, N, wv, std::make_index_sequence<PROL / 4>{});
#pragma unroll
    for (int i = 0; i < 16; ++i)             // zero slots 48..63 (NaN guard)
        xs[PROL * SLOTD + i * D_DIM + tid] = 0.0f;

    float wf0[4];
    loadA(wf0, smb, n0, g, k0, 0, std::make_index_sequence<4>{});
    writeA(Al[0], wf0, n0, g, k0, 0, N);

    float szc[4];
    loadSZ(szc, szb, n0, q4, N, std::make_index_sequence<4>{});
    __syncthreads();

    // ---- main loop ----
#pragma unroll 1
    for (int m = 0; m < NI; ++m) {
        const int R0m = n0 + RITER * m;
        const bool more = (m < NI - 1);

        // phase 1: issue next-tile DMA first (vmcnt accounting), then
        // next-iter A/size loads (land under compute)
        float wfn[4];
        float szn[4];
        if (more) {
            stage_iter(xs, xlane, n0 - CEN, m, N, wv);
            loadA(wfn, smb, R0m + RITER, g, k0, m + 1,
                  std::make_index_sequence<4>{});
            loadSZ(szn, szb, R0m + RITER, q4, N, std::make_index_sequence<4>{});
        }
        __builtin_amdgcn_sched_barrier(0);

        // phase 2: MFMA compute from the ring (identity slots)
        f32x4 acc[4] = {};
        compute(acc, xsb, Al[m & 1], g, q8, std::make_index_sequence<4>{});
        epi(acc, szc, obase, R0m, std::make_index_sequence<16>{});

        // phase 3: write next iter's A tile (other buffer) + sz handoff
        if (more) {
            writeA(Al[(m + 1) & 1], wfn, R0m + RITER, g, k0, m + 1, N);
#pragma unroll
            for (int j = 0; j < 4; ++j) szc[j] = szn[j];
        }

        // counted barrier: 4 A + 1 sz loads + 16 stores younger than the
        // 4 DMAs -> vmcnt(21); lgkmcnt(0) publishes writeA before barrier.
        __builtin_amdgcn_sched_barrier(0);
        asm volatile("s_waitcnt vmcnt(21) lgkmcnt(0)" ::: "memory");
        __builtin_amdgcn_s_barrier();
        __builtin_amdgcn_sched_barrier(0);
    }
}

extern "C" void kernel_launch(void* const* d_in, const int* in_sizes, int n_in,
                              void* d_out, int out_size, void* d_ws, size_t ws_size,
                              hipStream_t stream) {
    const float* x  = (const float*)d_in[0];
    const float* sz = (const float*)d_in[1];
    const float* sm = (const float*)d_in[2];
    float* out = (float*)d_out;

    const int B = 8;
    const int N = 16384;

    dim3 grid((N / CHUNK) * B, 1, 1);   // 64 x 8 = 512 blocks, XCD-swizzled
    dim3 block(256, 1, 1);
    local_enc_kernel<<<grid, block, 0, stream>>>(x, sz, sm, out, N);
}